// Round 8
// baseline (614.387 us; speedup 1.0000x reference)
//
#include <hip/hip_runtime.h>
#include <hip/hip_bf16.h>
#include <math.h>

#define BB 32
#define SS 512
#define DD 256
#define HH 8
#define HDIM 32
#define FFNN 128
#define NROWS (BB*SS)        // 16384
#define NELEM (NROWS*DD)     // 4194304

using bf16 = __hip_bfloat16;
typedef __attribute__((ext_vector_type(8))) short short8;
typedef __attribute__((ext_vector_type(4))) float floatx4;

static __device__ __forceinline__ float bf2f(bf16 x) { return __bfloat162float(x); }
static __device__ __forceinline__ bf16  f2bf(float x) { return __float2bfloat16(x); }
static __device__ __forceinline__ short f2bfs(float x) {
    bf16 b = __float2bfloat16(x);
    return __builtin_bit_cast(short, b);
}

// ---------- v dtype probe ----------
__global__ void init_flag(int* flag) { *flag = 0; }
__global__ __launch_bounds__(256) void detect_v(const int* __restrict__ v, int* __restrict__ flag) {
    int i = blockIdx.x * 256 + threadIdx.x;
    if (v[2 * i + 1] != 0) atomicOr(flag, 1);
}

// ---------- embed: X = relu(emb[v]), emb row 0 forced to 0; X lives in d_out ----------
__global__ __launch_bounds__(256) void embed_kernel(const int* __restrict__ v,
                                                    const float* __restrict__ emb,
                                                    const int* __restrict__ flag,
                                                    float* __restrict__ X) {
    int idx = blockIdx.x * 256 + threadIdx.x;
    int d = idx & (DD - 1);
    int row = idx >> 8;
    int tok = (*flag) ? v[row] : v[2 * row];
    float val = 0.0f;
    if (tok != 0) {
        val = emb[tok * DD + d];
        val = val > 0.0f ? val : 0.0f;
    }
    X[idx] = val;
}

// ---------- xPos tables: xpt[s*16+jf] = {cos*sm, sin*sm, cos/sm, sin/sm} ----------
__global__ __launch_bounds__(256) void xpos_table_kernel(float4* __restrict__ xpt) {
    int idx = blockIdx.x * 256 + threadIdx.x;    // 8192 = 512*16
    int jf = idx & 15, s = idx >> 4;
    float base = (2.0f * jf + 12.8f) / 44.8f;
    float sm = powf(base, (float)s * (1.0f / 512.0f));
    float ang = (float)s * powf(10000.0f, -(float)jf / 16.0f);
    float sn, cs;
    sincosf(ang, &sn, &cs);
    xpt[idx] = float4{cs * sm, sn * sm, cs / sm, sn / sm};
}

// ---------- fused layernorm: Xn = LN(X)*w+b  (bf16 out) ----------
__global__ __launch_bounds__(256) void ln_norm_kernel(const float* __restrict__ X,
                                                      const float* __restrict__ w,
                                                      const float* __restrict__ b,
                                                      short* __restrict__ Xn) {
    int row = blockIdx.x;
    int d = threadIdx.x;
    float x = X[(size_t)row * DD + d];
    float s1 = x, s2 = x * x;
    #pragma unroll
    for (int off = 1; off < 64; off <<= 1) {
        s1 += __shfl_xor(s1, off);
        s2 += __shfl_xor(s2, off);
    }
    __shared__ float p1[4], p2[4], st[2];
    int wid = threadIdx.x >> 6;
    if ((threadIdx.x & 63) == 0) { p1[wid] = s1; p2[wid] = s2; }
    __syncthreads();
    if (threadIdx.x == 0) {
        float t1 = p1[0] + p1[1] + p1[2] + p1[3];
        float t2 = p2[0] + p2[1] + p2[2] + p2[3];
        float mu = t1 * (1.0f / DD);
        float var = t2 * (1.0f / DD) - mu * mu;
        st[0] = mu; st[1] = rsqrtf(var + 1e-5f);
    }
    __syncthreads();
    Xn[(size_t)row * DD + d] = f2bfs((x - st[0]) * st[1] * w[d] + b[d]);
}

// ---------- weight packing: f32 -> bf16, [n][k] layout ----------
__global__ __launch_bounds__(256) void pack_qkvg(const float* __restrict__ WQ, const float* __restrict__ WK,
                                                 const float* __restrict__ WV, const float* __restrict__ WG,
                                                 bf16* __restrict__ dst) {
    int idx = blockIdx.x * 256 + threadIdx.x;       // 3*1024*256
    int k = idx & 255, n = (idx >> 8) & 1023, l = idx >> 18;
    int seg = n >> 8, n8 = n & 255;
    float val;
    if (seg < 3) {
        const float* W = (seg == 0) ? WQ : (seg == 1) ? WK : WV;
        int h = n8 >> 5, e = n8 & 31;
        val = W[(((size_t)l * 8 + h) * 256 + k) * 32 + e];
    } else {
        val = WG[(size_t)l * 65536 + k * 256 + n8];
    }
    dst[((size_t)l * 1024 + n) * 256 + k] = f2bf(val);
}
__global__ __launch_bounds__(256) void pack_wo(const float* __restrict__ WO, bf16* __restrict__ dst) {
    int idx = blockIdx.x * 256 + threadIdx.x;       // 3*256*256
    int k = idx & 255, n = (idx >> 8) & 255, l = idx >> 16;
    dst[((size_t)l * 256 + n) * 256 + k] = f2bf(WO[(size_t)l * 65536 + k * 256 + n]);
}
__global__ __launch_bounds__(256) void pack_w1(const float* __restrict__ w1, bf16* __restrict__ dst) {
    int idx = blockIdx.x * 256 + threadIdx.x;       // 3*128*256
    int k = idx & 255, n = (idx >> 8) & 127, l = idx >> 15;
    dst[((size_t)l * 128 + n) * 256 + k] = f2bf(w1[(size_t)l * 32768 + k * 128 + n]);
}
__global__ __launch_bounds__(256) void pack_w2(const float* __restrict__ w2, bf16* __restrict__ dst) {
    int idx = blockIdx.x * 256 + threadIdx.x;       // 3*256*128
    int k = idx & 127, n = (idx >> 7) & 255, l = idx >> 15;
    dst[((size_t)l * 256 + n) * 128 + k] = f2bf(w2[(size_t)l * 32768 + k * 256 + n]);
}

// ---------- MFMA GEMM, barrier-free: fragments loaded DIRECTLY from global ----------
// A row-major bf16 [M][lda]; B packed [N][K] -> both A-frag and B-frag are 16B
// contiguous per lane. No LDS, no __syncthreads, compiler emits per-use vmcnt(N).
// Block = 2x2 waves; per-wave TMxTN tiles of 16x16x32.
// EPI: 0 = xPos via table (cols<512) + bf16 store; 1 = [bias]+f32 residual add/store;
//      2 = bias + exact gelu + bf16 store
template<int TM, int TN, int EPI, int KK>
__global__ __launch_bounds__(256) void mfma_gemm(const short* __restrict__ A, int lda,
                                                 const short* __restrict__ Bp,
                                                 const float* __restrict__ bias,
                                                 float* __restrict__ addsrc, int ldadd,
                                                 const float4* __restrict__ xpt,
                                                 void* __restrict__ Cv, int ldc) {
    const int tid = threadIdx.x;
    const int wave = tid >> 6, lane = tid & 63, lo = lane & 15, quad = lane >> 4;
    const int wm = wave >> 1, wn = wave & 1;
    const int row0 = blockIdx.y * 32 * TM, col0 = blockIdx.x * 32 * TN;

    floatx4 acc[TM][TN];
    #pragma unroll
    for (int i = 0; i < TM; ++i)
        #pragma unroll
        for (int j = 0; j < TN; ++j) acc[i][j] = floatx4{0.f, 0.f, 0.f, 0.f};

    const short* Abase = A + (size_t)(row0 + wm * TM * 16 + lo) * lda + quad * 8;
    const short* Bbase = Bp + (size_t)(col0 + wn * TN * 16 + lo) * KK + quad * 8;

    #pragma unroll
    for (int k0 = 0; k0 < KK; k0 += 32) {
        short8 af[TM], bfr[TN];
        #pragma unroll
        for (int t = 0; t < TM; ++t)
            af[t] = *(const short8*)(Abase + (size_t)(t * 16) * lda + k0);
        #pragma unroll
        for (int t = 0; t < TN; ++t)
            bfr[t] = *(const short8*)(Bbase + (size_t)(t * 16) * KK + k0);
        #pragma unroll
        for (int ti = 0; ti < TM; ++ti)
            #pragma unroll
            for (int tj = 0; tj < TN; ++tj)
                acc[ti][tj] = __builtin_amdgcn_mfma_f32_16x16x32_bf16(af[ti], bfr[tj], acc[ti][tj], 0, 0, 0);
    }

    // epilogue: C/D layout col=lo, row=quad*4+r
    #pragma unroll
    for (int ti = 0; ti < TM; ++ti) {
        #pragma unroll
        for (int tj = 0; tj < TN; ++tj) {
            int colb = col0 + (wn * TN + tj) * 16 + lo;
            #pragma unroll
            for (int r = 0; r < 4; ++r) {
                int row = row0 + (wm * TM + ti) * 16 + quad * 4 + r;
                float v = acc[ti][tj][r];
                if (EPI == 0) {
                    int seg = colb >> 8;            // wave-uniform
                    if (seg < 2) {
                        int s = row & (SS - 1);
                        int jf = (colb & 31) >> 1;
                        float4 t = xpt[s * 16 + jf];
                        float cs = (seg == 0) ? t.x : t.z;
                        float sn = (seg == 0) ? t.y : t.w;
                        float p = __shfl_xor(v, 1);
                        v = (lo & 1) ? (v * cs + p * sn) : (v * cs - p * sn);
                    }
                    ((bf16*)Cv)[(size_t)row * ldc + colb] = f2bf(v);
                } else if (EPI == 1) {
                    if (bias) v += bias[colb];
                    v += addsrc[(size_t)row * ldadd + colb];
                    ((float*)Cv)[(size_t)row * ldc + colb] = v;
                } else {
                    v += bias[colb];
                    v = 0.5f * v * (1.0f + erff(v * 0.70710678118f));
                    ((bf16*)Cv)[(size_t)row * ldc + colb] = f2bf(v);
                }
            }
        }
    }
}

// ---------- MFMA retention + groupnorm(32) + silu gate ----------
#define VSTRIDE 42
__global__ __launch_bounds__(256) void retention_mfma_kernel(bf16* __restrict__ QKVG,
                                                             const float* __restrict__ gnw,
                                                             const float* __restrict__ gnb) {
    __shared__ __align__(16) short Vl[4][32 * VSTRIDE];
    __shared__ __align__(16) short Pl[4][16 * 40];
    int wslot = threadIdx.x >> 6;
    int lane = threadIdx.x & 63;
    int qi = blockIdx.x >> 6;
    int bh = ((blockIdx.x & 63) << 2) | wslot;
    int b = bh >> 3, h = bh & 7;
    int q0 = qi * 16;
    int lo = lane & 15, quad = lane >> 4;

    const float la0 = -3.46573590280f, la1 = -6.23832462504f;
    float gamma = 1.0f - expf(la0 + (float)h * (la1 - la0) / 7.0f);
    float lg2 = log2f(gamma);

    const size_t base = (size_t)b * SS * 1024;
    const short* QKVGs = (const short*)QKVG;

    short8 qfrag = *(const short8*)(QKVGs + base + (size_t)(q0 + lo) * 1024 + h * HDIM + quad * 8);

    floatx4 o0 = {0.f, 0.f, 0.f, 0.f}, o1 = {0.f, 0.f, 0.f, 0.f};
    short* Vw = Vl[wslot];
    short* Pw = Pl[wslot];
    int nch = (qi >> 1) + 1;

    for (int ch = 0; ch < nch; ++ch) {
        int t0 = ch * 32;
        const short* Kb = QKVGs + base + 256 + h * HDIM + quad * 8;
        short8 kf0 = *(const short8*)(Kb + (size_t)(t0 + lo) * 1024);
        short8 kf1 = *(const short8*)(Kb + (size_t)(t0 + 16 + lo) * 1024);
        {
            int r = lane >> 2, d = (lane & 3) * 8;
            const uint* Vg1 = (const uint*)(QKVGs + base + (size_t)(t0 + r) * 1024 + 512 + h * HDIM + d);
            const uint* Vg2 = (const uint*)(QKVGs + base + (size_t)(t0 + 16 + r) * 1024 + 512 + h * HDIM + d);
            uint* L1 = (uint*)(Vw + r * VSTRIDE + d);
            uint* L2 = (uint*)(Vw + (16 + r) * VSTRIDE + d);
            #pragma unroll
            for (int w = 0; w < 4; ++w) { L1[w] = Vg1[w]; L2[w] = Vg2[w]; }
        }
        floatx4 z = {0.f, 0.f, 0.f, 0.f};
        floatx4 s0 = __builtin_amdgcn_mfma_f32_16x16x32_bf16(qfrag, kf0, z, 0, 0, 0);
        floatx4 s1 = __builtin_amdgcn_mfma_f32_16x16x32_bf16(qfrag, kf1, z, 0, 0, 0);
        #pragma unroll
        for (int r = 0; r < 4; ++r) {
            int q = q0 + quad * 4 + r;
            int t = t0 + lo;
            float w0 = (q >= t)      ? exp2f((float)(q - t) * lg2)      : 0.0f;
            float w1 = (q >= t + 16) ? exp2f((float)(q - t - 16) * lg2) : 0.0f;
            Pw[(quad * 4 + r) * 40 + lo]      = f2bfs(s0[r] * w0);
            Pw[(quad * 4 + r) * 40 + 16 + lo] = f2bfs(s1[r] * w1);
        }
        __syncthreads();
        short8 pf = *(const short8*)(Pw + lo * 40 + quad * 8);
        short8 vf0, vf1;
        #pragma unroll
        for (int j = 0; j < 8; ++j) {
            vf0[j] = Vw[(quad * 8 + j) * VSTRIDE + lo];
            vf1[j] = Vw[(quad * 8 + j) * VSTRIDE + 16 + lo];
        }
        o0 = __builtin_amdgcn_mfma_f32_16x16x32_bf16(pf, vf0, o0, 0, 0, 0);
        o1 = __builtin_amdgcn_mfma_f32_16x16x32_bf16(pf, vf1, o1, 0, 0, 0);
        __syncthreads();
    }

    float gw0 = gnw[h * HDIM + lo], gw1 = gnw[h * HDIM + 16 + lo];
    float gb0 = gnb[h * HDIM + lo], gb1 = gnb[h * HDIM + 16 + lo];
    bf16* QK = QKVG;
    #pragma unroll
    for (int r = 0; r < 4; ++r) {
        float y0 = o0[r], y1 = o1[r];
        float s = y0 + y1, ss = y0 * y0 + y1 * y1;
        #pragma unroll
        for (int off = 1; off < 16; off <<= 1) {
            s  += __shfl_xor(s, off);
            ss += __shfl_xor(ss, off);
        }
        float mu = s * (1.0f / HDIM);
        float var = ss * (1.0f / HDIM) - mu * mu;
        float rstd = rsqrtf(var + 1e-5f);
        int q = q0 + quad * 4 + r;
        size_t rowb = base + (size_t)q * 1024;
        float g0 = bf2f(QK[rowb + 768 + h * HDIM + lo]);
        float g1 = bf2f(QK[rowb + 768 + h * HDIM + 16 + lo]);
        float t0v = g0 / (1.0f + expf(-g0)) * ((y0 - mu) * rstd * gw0 + gb0);
        float t1v = g1 / (1.0f + expf(-g1)) * ((y1 - mu) * rstd * gw1 + gb1);
        QK[rowb + h * HDIM + lo]      = f2bf(t0v);
        QK[rowb + h * HDIM + 16 + lo] = f2bf(t1v);
    }
}

extern "C" void kernel_launch(void* const* d_in, const int* in_sizes, int n_in,
                              void* d_out, int out_size, void* d_ws, size_t ws_size,
                              hipStream_t stream) {
    const int*   v    = (const int*)d_in[0];
    const float* emb  = (const float*)d_in[1];
    const float* WQ   = (const float*)d_in[2];
    const float* WK   = (const float*)d_in[3];
    const float* WV   = (const float*)d_in[4];
    const float* WG   = (const float*)d_in[5];
    const float* WO   = (const float*)d_in[6];
    const float* gn_w = (const float*)d_in[7];
    const float* gn_b = (const float*)d_in[8];
    const float* ln1w = (const float*)d_in[9];
    const float* ln1b = (const float*)d_in[10];
    const float* ln2w = (const float*)d_in[11];
    const float* ln2b = (const float*)d_in[12];
    const float* w1   = (const float*)d_in[13];
    const float* b1   = (const float*)d_in[14];
    const float* w2   = (const float*)d_in[15];
    const float* b2   = (const float*)d_in[16];

    float* X = (float*)d_out;                    // residual stream (f32) in d_out

    float* base  = (float*)d_ws;
    int*   flag  = (int*)base;
    short* Xn    = (short*)(base + 16);          // NROWS*256 bf16
    bf16*  QKVG  = (bf16*)(Xn + (size_t)NROWS * 256);  // NROWS*1024
    bf16*  Hf    = QKVG + (size_t)NROWS * 1024;  // NROWS*128
    bf16*  WqkvgP = Hf + (size_t)NROWS * 128;    // 3*1024*256
    bf16*  WoP   = WqkvgP + 3 * 1024 * 256;      // 3*256*256
    bf16*  W1P   = WoP + 3 * 256 * 256;          // 3*128*256
    bf16*  W2P   = W1P + 3 * 128 * 256;          // 3*256*128
    float4* xpt  = (float4*)(W2P + 3 * 256 * 128); // 512*16 float4

    init_flag<<<1, 1, 0, stream>>>(flag);
    detect_v<<<32, 256, 0, stream>>>(v, flag);
    embed_kernel<<<NELEM / 256, 256, 0, stream>>>(v, emb, flag, X);
    xpos_table_kernel<<<32, 256, 0, stream>>>(xpt);
    pack_qkvg<<<3072, 256, 0, stream>>>(WQ, WK, WV, WG, WqkvgP);
    pack_wo<<<768, 256, 0, stream>>>(WO, WoP);
    pack_w1<<<384, 256, 0, stream>>>(w1, W1P);
    pack_w2<<<384, 256, 0, stream>>>(w2, W2P);

    for (int i = 0; i < 3; ++i) {
        // Xn = LN1(X) (bf16)
        ln_norm_kernel<<<NROWS, 256, 0, stream>>>(X, ln1w + i * DD, ln1b + i * DD, Xn);
        // QKVG = xpos(Xn @ [WQ|WK|WV|WG])  (bf16)
        mfma_gemm<4, 4, 0, 256><<<dim3(8, 128), 256, 0, stream>>>(Xn, DD,
                                                                  (const short*)(WqkvgP + (size_t)i * 1024 * 256),
                                                                  nullptr, nullptr, 0, xpt, QKVG, 1024);
        retention_mfma_kernel<<<2048, 256, 0, stream>>>(QKVG, gn_w + i * DD, gn_b + i * DD);
        // X += T @ WO
        mfma_gemm<2, 2, 1, 256><<<dim3(4, 256), 256, 0, stream>>>((const short*)QKVG, 1024,
                                                                  (const short*)(WoP + (size_t)i * 256 * 256),
                                                                  nullptr, X, DD, nullptr, X, DD);
        // Xn = LN2(X) (bf16)
        ln_norm_kernel<<<NROWS, 256, 0, stream>>>(X, ln2w + i * DD, ln2b + i * DD, Xn);
        // Hf = gelu(Xn @ w1 + b1)  (bf16)
        mfma_gemm<2, 2, 2, 256><<<dim3(2, 256), 256, 0, stream>>>(Xn, DD,
                                                                  (const short*)(W1P + (size_t)i * 128 * 256),
                                                                  b1 + i * FFNN, nullptr, 0, nullptr, Hf, FFNN);
        // X += Hf @ w2 + b2
        mfma_gemm<2, 2, 1, 128><<<dim3(4, 256), 256, 0, stream>>>((const short*)Hf, FFNN,
                                                                  (const short*)(W2P + (size_t)i * 256 * 128),
                                                                  b2 + i * DD, X, DD, nullptr, X, DD);
    }
}